// Round 3
// baseline (477.341 us; speedup 1.0000x reference)
//
#include <hip/hip_runtime.h>

#define NN 50000
#define NE 500000
#define FIN 16
#define FOUT 16
#define HID 64
#define TROW 1040   // (HID+1)*16 floats per node: j=0..63 = W2 part, j=64 = b2 part

// ===========================================================================
// MAIN PATH (~249 MB ws):
//   msg[e,o] = T[s][64][o] + sum_j h[e,j]*T[s][j][o];  T[n][j][o]=sum_i x[n,i]*W2[j][i*16+o]
//   2.1 kFMA/edge instead of 18.7 k. Edges counting-sorted by src so T-row
//   loads are wave-shared (L1 broadcast, ~7 distinct lines/instr not 64).
// ===========================================================================

__global__ __launch_bounds__(256) void w2r_prep(
    const float* __restrict__ W2, const float* __restrict__ b2,
    float* __restrict__ W2R)
{
    const int t = blockIdx.x * blockDim.x + threadIdx.x;
    if (t >= 65 * 256) return;
    const int j = t >> 8;
    const int col = t & 255;          // col = i*16 + o
    const int i = col >> 4, o = col & 15;
    const float v = (j < 64) ? W2[j * 256 + col] : b2[col];
    W2R[j * 256 + o * 16 + i] = v;    // W2R[j][o][i]
}

__global__ __launch_bounds__(256) void count_src(
    const int* __restrict__ src, int* __restrict__ deg_s, int* __restrict__ pos_s)
{
    const int e = blockIdx.x * blockDim.x + threadIdx.x;
    if (e >= NE) return;
    pos_s[e] = atomicAdd(deg_s + src[e], 1);
}

__global__ __launch_bounds__(1024) void dgc_scan(
    const int* __restrict__ deg, int* __restrict__ offs, int n)
{
    __shared__ int wsum[16];
    const int tid = threadIdx.x;
    const int lane = tid & 63;
    const int wid = tid >> 6;
    int carry = 0;
    for (int base = 0; base < n; base += 1024) {
        const int idx = base + tid;
        const int v = (idx < n) ? deg[idx] : 0;
        int s = v;
        #pragma unroll
        for (int d = 1; d < 64; d <<= 1) {
            int t = __shfl_up(s, d, 64);
            if (lane >= d) s += t;
        }
        if (lane == 63) wsum[wid] = s;
        __syncthreads();
        if (wid == 0 && lane < 16) {
            int w = wsum[lane];
            #pragma unroll
            for (int d = 1; d < 16; d <<= 1) {
                int t = __shfl_up(w, d, 64);
                if (lane >= d) w += t;
            }
            wsum[lane] = w;
        }
        __syncthreads();
        const int wpre = (wid == 0) ? 0 : wsum[wid - 1];
        if (idx < n) offs[idx] = carry + wpre + (s - v);
        carry += wsum[15];
        __syncthreads();
    }
    if (tid == 0) offs[n] = carry;
}

__global__ __launch_bounds__(256) void scatter_src(
    const int* __restrict__ src, const int* __restrict__ pos_s,
    const int* __restrict__ offs_s, int* __restrict__ eidx_s)
{
    const int e = blockIdx.x * blockDim.x + threadIdx.x;
    if (e >= NE) return;
    eidx_s[offs_s[src[e]] + pos_s[e]] = e;
}

// T[n][j][o] = sum_i x[n,i]*W2R[j][o][i].  thread = (n,o); stores coalesce per j.
__global__ __launch_bounds__(256) void tprep(
    const float* __restrict__ x, const float* __restrict__ W2R,
    float* __restrict__ T)
{
    const int t = blockIdx.x * blockDim.x + threadIdx.x;
    if (t >= NN * 16) return;
    const int n = t >> 4;
    const int o = t & 15;

    float xr[16];
    {
        const float4* p = reinterpret_cast<const float4*>(x) + (size_t)n * 4;
        float4 a = p[0], b = p[1], c = p[2], d = p[3];
        xr[0]=a.x; xr[1]=a.y; xr[2]=a.z;  xr[3]=a.w;
        xr[4]=b.x; xr[5]=b.y; xr[6]=b.z;  xr[7]=b.w;
        xr[8]=c.x; xr[9]=c.y; xr[10]=c.z; xr[11]=c.w;
        xr[12]=d.x; xr[13]=d.y; xr[14]=d.z; xr[15]=d.w;
    }

    float* trow = T + (size_t)n * TROW;
    for (int j = 0; j < 65; ++j) {
        const float4* wp = reinterpret_cast<const float4*>(W2R + j * 256 + o * 16);
        float4 wa = wp[0], wb = wp[1], wc = wp[2], wd = wp[3];
        float s;
        s  = xr[0]*wa.x;           s = fmaf(xr[1],  wa.y, s); s = fmaf(xr[2],  wa.z, s); s = fmaf(xr[3],  wa.w, s);
        s = fmaf(xr[4],  wb.x, s); s = fmaf(xr[5],  wb.y, s); s = fmaf(xr[6],  wb.z, s); s = fmaf(xr[7],  wb.w, s);
        s = fmaf(xr[8],  wc.x, s); s = fmaf(xr[9],  wc.y, s); s = fmaf(xr[10], wc.z, s); s = fmaf(xr[11], wc.w, s);
        s = fmaf(xr[12], wd.x, s); s = fmaf(xr[13], wd.y, s); s = fmaf(xr[14], wd.z, s); s = fmaf(xr[15], wd.w, s);
        trow[j * 16 + o] = s;
    }
}

__global__ __launch_bounds__(256) void edge_msg(
    const int* __restrict__ eidx_s, const int* __restrict__ src,
    const int* __restrict__ dst, const float* __restrict__ ef,
    const float* __restrict__ W1, const float* __restrict__ b1,
    const float* __restrict__ T, float* __restrict__ msgbuf,
    int* __restrict__ deg_d, int* __restrict__ posd)
{
    const int k = blockIdx.x * blockDim.x + threadIdx.x;
    if (k >= NE) return;
    const int e = eidx_s[k];
    const int s = src[e];

    float efv[16];
    {
        const float4* p = reinterpret_cast<const float4*>(ef) + (size_t)e * 4;
        float4 a = p[0], b = p[1], c = p[2], d = p[3];
        efv[0]=a.x; efv[1]=a.y; efv[2]=a.z;  efv[3]=a.w;
        efv[4]=b.x; efv[5]=b.y; efv[6]=b.z;  efv[7]=b.w;
        efv[8]=c.x; efv[9]=c.y; efv[10]=c.z; efv[11]=c.w;
        efv[12]=d.x; efv[13]=d.y; efv[14]=d.z; efv[15]=d.w;
    }

    const float* tr = T + (size_t)s * TROW;
    float m[16];
    {
        const float4* bp = reinterpret_cast<const float4*>(tr + 64 * 16);
        float4 a = bp[0], b = bp[1], c = bp[2], d = bp[3];
        m[0]=a.x; m[1]=a.y; m[2]=a.z;  m[3]=a.w;
        m[4]=b.x; m[5]=b.y; m[6]=b.z;  m[7]=b.w;
        m[8]=c.x; m[9]=c.y; m[10]=c.z; m[11]=c.w;
        m[12]=d.x; m[13]=d.y; m[14]=d.z; m[15]=d.w;
    }

    for (int j = 0; j < HID; ++j) {
        float hj = b1[j];
        #pragma unroll
        for (int i = 0; i < 16; ++i)
            hj = fmaf(efv[i], W1[i * HID + j], hj);
        hj = fmaxf(hj, 0.f);

        const float4* tp = reinterpret_cast<const float4*>(tr + j * 16);
        float4 a = tp[0], b = tp[1], c = tp[2], d = tp[3];
        m[0]  = fmaf(hj, a.x, m[0]);  m[1]  = fmaf(hj, a.y, m[1]);
        m[2]  = fmaf(hj, a.z, m[2]);  m[3]  = fmaf(hj, a.w, m[3]);
        m[4]  = fmaf(hj, b.x, m[4]);  m[5]  = fmaf(hj, b.y, m[5]);
        m[6]  = fmaf(hj, b.z, m[6]);  m[7]  = fmaf(hj, b.w, m[7]);
        m[8]  = fmaf(hj, c.x, m[8]);  m[9]  = fmaf(hj, c.y, m[9]);
        m[10] = fmaf(hj, c.z, m[10]); m[11] = fmaf(hj, c.w, m[11]);
        m[12] = fmaf(hj, d.x, m[12]); m[13] = fmaf(hj, d.y, m[13]);
        m[14] = fmaf(hj, d.z, m[14]); m[15] = fmaf(hj, d.w, m[15]);
    }

    float4* mr = reinterpret_cast<float4*>(msgbuf + (size_t)k * 16);
    mr[0] = make_float4(m[0], m[1], m[2], m[3]);
    mr[1] = make_float4(m[4], m[5], m[6], m[7]);
    mr[2] = make_float4(m[8], m[9], m[10], m[11]);
    mr[3] = make_float4(m[12], m[13], m[14], m[15]);

    posd[k] = atomicAdd(deg_d + dst[e], 1);
}

__global__ __launch_bounds__(256) void scatter_dst(
    const int* __restrict__ eidx_s, const int* __restrict__ dst,
    const int* __restrict__ posd, const int* __restrict__ offs_d,
    int* __restrict__ loc_d)
{
    const int k = blockIdx.x * blockDim.x + threadIdx.x;
    if (k >= NE) return;
    loc_d[offs_d[dst[eidx_s[k]]] + posd[k]] = k;
}

__global__ __launch_bounds__(256) void gather_mean(
    const float* __restrict__ msgbuf, const int* __restrict__ offs_d,
    const int* __restrict__ loc_d, const float* __restrict__ x,
    const float* __restrict__ bias, float* __restrict__ out)
{
    const int t = blockIdx.x * blockDim.x + threadIdx.x;
    if (t >= NN * FOUT) return;
    const int n = t >> 4;
    const int o = t & 15;
    const int beg = offs_d[n], end = offs_d[n + 1];
    float s = 0.f;
    for (int kk = beg; kk < end; ++kk)
        s += msgbuf[(size_t)loc_d[kk] * 16 + o];
    const int d = end - beg;
    const float v = (d > 0) ? (s / (float)d) : x[t];
    out[t] = v + bias[o];
}

// ===========================================================================
// FALLBACK (round-2 proven path, ~36.4 MB ws)
// ===========================================================================
__global__ __launch_bounds__(256) void dgc_edge_csr(
    const float* __restrict__ x, const float* __restrict__ ef,
    const int* __restrict__ src, const int* __restrict__ dst,
    const float* __restrict__ W1, const float* __restrict__ b1,
    const float* __restrict__ W2, const float* __restrict__ b2,
    float* __restrict__ msg, int* __restrict__ pos, int* __restrict__ deg)
{
    const int e = blockIdx.x * blockDim.x + threadIdx.x;
    if (e >= NE) return;
    float efv[16];
    {
        const float4* p = reinterpret_cast<const float4*>(ef) + (size_t)e * 4;
        float4 a = p[0], b = p[1], c = p[2], d = p[3];
        efv[0]=a.x; efv[1]=a.y; efv[2]=a.z;  efv[3]=a.w;
        efv[4]=b.x; efv[5]=b.y; efv[6]=b.z;  efv[7]=b.w;
        efv[8]=c.x; efv[9]=c.y; efv[10]=c.z; efv[11]=c.w;
        efv[12]=d.x; efv[13]=d.y; efv[14]=d.z; efv[15]=d.w;
    }
    const int s = src[e];
    float xs[16];
    {
        const float4* p = reinterpret_cast<const float4*>(x) + (size_t)s * 4;
        float4 a = p[0], b = p[1], c = p[2], d = p[3];
        xs[0]=a.x; xs[1]=a.y; xs[2]=a.z;  xs[3]=a.w;
        xs[4]=b.x; xs[5]=b.y; xs[6]=b.z;  xs[7]=b.w;
        xs[8]=c.x; xs[9]=c.y; xs[10]=c.z; xs[11]=c.w;
        xs[12]=d.x; xs[13]=d.y; xs[14]=d.z; xs[15]=d.w;
    }
    float m[16];
    #pragma unroll
    for (int o = 0; o < 16; ++o) m[o] = 0.f;
    #pragma unroll
    for (int i = 0; i < 16; ++i) {
        const float xi = xs[i];
        #pragma unroll
        for (int o = 0; o < 16; ++o) m[o] = fmaf(xi, b2[i * 16 + o], m[o]);
    }
    for (int j = 0; j < HID; ++j) {
        float hj = b1[j];
        #pragma unroll
        for (int i = 0; i < 16; ++i) hj = fmaf(efv[i], W1[i * HID + j], hj);
        hj = fmaxf(hj, 0.f);
        const float* __restrict__ w2r = W2 + (size_t)j * 256;
        float t[16];
        #pragma unroll
        for (int o = 0; o < 16; ++o) t[o] = 0.f;
        #pragma unroll
        for (int i = 0; i < 16; ++i) {
            const float xi = xs[i];
            #pragma unroll
            for (int o = 0; o < 16; ++o) t[o] = fmaf(xi, w2r[i * 16 + o], t[o]);
        }
        #pragma unroll
        for (int o = 0; o < 16; ++o) m[o] = fmaf(hj, t[o], m[o]);
    }
    float4* mr = reinterpret_cast<float4*>(msg + (size_t)e * 16);
    mr[0] = make_float4(m[0], m[1], m[2], m[3]);
    mr[1] = make_float4(m[4], m[5], m[6], m[7]);
    mr[2] = make_float4(m[8], m[9], m[10], m[11]);
    mr[3] = make_float4(m[12], m[13], m[14], m[15]);
    pos[e] = atomicAdd(deg + dst[e], 1);
}

__global__ __launch_bounds__(256) void dgc_scatter(
    const int* __restrict__ dst, const int* __restrict__ pos,
    const int* __restrict__ offs, int* __restrict__ eidx)
{
    const int e = blockIdx.x * blockDim.x + threadIdx.x;
    if (e >= NE) return;
    eidx[offs[dst[e]] + pos[e]] = e;
}

__global__ __launch_bounds__(256) void dgc_gather(
    const float* __restrict__ msg, const int* __restrict__ offs,
    const int* __restrict__ eidx, const float* __restrict__ x,
    const float* __restrict__ bias, float* __restrict__ out)
{
    const int t = blockIdx.x * blockDim.x + threadIdx.x;
    if (t >= NN * FOUT) return;
    const int n = t >> 4;
    const int o = t & 15;
    const int beg = offs[n], end = offs[n + 1];
    float s = 0.f;
    for (int k = beg; k < end; ++k)
        s += msg[(size_t)eidx[k] * 16 + o];
    const int d = end - beg;
    const float v = (d > 0) ? (s / (float)d) : x[t];
    out[t] = v + bias[o];
}

extern "C" void kernel_launch(void* const* d_in, const int* in_sizes, int n_in,
                              void* d_out, int out_size, void* d_ws, size_t ws_size,
                              hipStream_t stream) {
    const float* x    = (const float*)d_in[0];
    const float* ef   = (const float*)d_in[1];
    const int*   src  = (const int*)d_in[2];
    const int*   dst  = (const int*)d_in[3];
    const float* W1   = (const float*)d_in[4];
    const float* b1   = (const float*)d_in[5];
    const float* W2   = (const float*)d_in[6];
    const float* b2   = (const float*)d_in[7];
    const float* bias = (const float*)d_in[8];
    float* out = (float*)d_out;

    float* T      = (float*)d_ws;                         // NN*TROW
    float* msgbuf = T + (size_t)NN * TROW;                // NE*16
    float* W2R    = msgbuf + (size_t)NE * 16;             // 65*256
    int*   deg_s  = (int*)(W2R + 65 * 256);               // NN
    int*   deg_d  = deg_s + NN;                           // NN
    int*   offs_s = deg_d + NN;                           // NN+1
    int*   offs_d = offs_s + NN + 1;                      // NN+1
    int*   pos_s  = offs_d + NN + 1;                      // NE
    int*   posd   = pos_s + NE;                           // NE
    int*   eidx_s = posd + NE;                            // NE
    int*   loc_d  = eidx_s + NE;                          // NE
    const size_t needed =
        ((size_t)NN * TROW + (size_t)NE * 16 + 65 * 256) * 4 +
        ((size_t)2 * NN + 2 * (NN + 1) + (size_t)4 * NE) * 4;

    if (ws_size >= needed) {
        hipMemsetAsync(deg_s, 0, (size_t)2 * NN * sizeof(int), stream);
        w2r_prep<<<(65 * 256 + 255) / 256, 256, 0, stream>>>(W2, b2, W2R);
        count_src<<<(NE + 255) / 256, 256, 0, stream>>>(src, deg_s, pos_s);
        dgc_scan<<<1, 1024, 0, stream>>>(deg_s, offs_s, NN);
        scatter_src<<<(NE + 255) / 256, 256, 0, stream>>>(src, pos_s, offs_s, eidx_s);
        tprep<<<(NN * 16 + 255) / 256, 256, 0, stream>>>(x, W2R, T);
        edge_msg<<<(NE + 255) / 256, 256, 0, stream>>>(
            eidx_s, src, dst, ef, W1, b1, T, msgbuf, deg_d, posd);
        dgc_scan<<<1, 1024, 0, stream>>>(deg_d, offs_d, NN);
        scatter_dst<<<(NE + 255) / 256, 256, 0, stream>>>(eidx_s, dst, posd, offs_d, loc_d);
        gather_mean<<<(NN * FOUT + 255) / 256, 256, 0, stream>>>(
            msgbuf, offs_d, loc_d, x, bias, out);
    } else {
        float* msg  = (float*)d_ws;
        int*   deg  = (int*)(msg + (size_t)NE * 16);
        int*   offs = deg + NN;
        int*   pos  = offs + NN + 1;
        int*   eidx = pos + NE;
        hipMemsetAsync(deg, 0, (size_t)NN * sizeof(int), stream);
        dgc_edge_csr<<<(NE + 255) / 256, 256, 0, stream>>>(
            x, ef, src, dst, W1, b1, W2, b2, msg, pos, deg);
        dgc_scan<<<1, 1024, 0, stream>>>(deg, offs, NN);
        dgc_scatter<<<(NE + 255) / 256, 256, 0, stream>>>(dst, pos, offs, eidx);
        dgc_gather<<<(NN * FOUT + 255) / 256, 256, 0, stream>>>(
            msg, offs, eidx, x, bias, out);
    }
}

// Round 4
// 385.763 us; speedup vs baseline: 1.2374x; 1.2374x over previous
//
#include <hip/hip_runtime.h>

#define NN 50000
#define NE 500000
#define FIN 16
#define FOUT 16
#define HID 64
#define TROW 1040   // (HID+1)*16 elems per node: j=0..63 = W2 part, j=64 = b2 part

typedef unsigned int  uint;
typedef unsigned short ushort;

__device__ __forceinline__ ushort f2bf(float f) {   // RNE f32->bf16
    uint u = __float_as_uint(f);
    u += 0x7fffu + ((u >> 16) & 1u);
    return (ushort)(u >> 16);
}
__device__ __forceinline__ float bflo(uint u) { return __uint_as_float(u << 16); }
__device__ __forceinline__ float bfhi(uint u) { return __uint_as_float(u & 0xffff0000u); }

// ===========================================================================
// MAIN PATH (~237 MB ws). Factorized: msg[e,o] = T[s][64][o] + sum_j h_j*T[s][j][o]
// T stored bf16 (104 MB): halves tprep writes + edge_msg reads; L1-resident rows.
// ===========================================================================

// W2R[j][o][i] = W2[j][i*16+o] (j<64), b2[i*16+o] (j==64)
__global__ __launch_bounds__(256) void w2r_prep(
    const float* __restrict__ W2, const float* __restrict__ b2,
    float* __restrict__ W2R)
{
    const int t = blockIdx.x * blockDim.x + threadIdx.x;
    if (t >= 65 * 256) return;
    const int j = t >> 8;
    const int col = t & 255;          // col = i*16 + o
    const int i = col >> 4, o = col & 15;
    const float v = (j < 64) ? W2[j * 256 + col] : b2[col];
    W2R[j * 256 + o * 16 + i] = v;
}

// one pass: src ranks (for src-sort) + dst degree histogram
__global__ __launch_bounds__(256) void count_both(
    const int* __restrict__ src, const int* __restrict__ dst,
    int* __restrict__ deg_s, int* __restrict__ pos_s, int* __restrict__ deg_d)
{
    const int e = blockIdx.x * blockDim.x + threadIdx.x;
    if (e >= NE) return;
    pos_s[e] = atomicAdd(deg_s + src[e], 1);
    atomicAdd(deg_d + dst[e], 1);
}

// two independent exclusive scans (block 0: A, block 1: B), n=NN each
__global__ __launch_bounds__(1024) void dgc_scan2(
    const int* __restrict__ degA, int* __restrict__ offA,
    const int* __restrict__ degB, int* __restrict__ offB)
{
    const int* __restrict__ deg = blockIdx.x ? degB : degA;
    int* __restrict__ offs      = blockIdx.x ? offB : offA;
    __shared__ int wsum[16];
    const int tid = threadIdx.x;
    const int lane = tid & 63;
    const int wid = tid >> 6;
    int carry = 0;
    for (int base = 0; base < NN; base += 1024) {
        const int idx = base + tid;
        const int v = (idx < NN) ? deg[idx] : 0;
        int s = v;
        #pragma unroll
        for (int d = 1; d < 64; d <<= 1) {
            int t = __shfl_up(s, d, 64);
            if (lane >= d) s += t;
        }
        if (lane == 63) wsum[wid] = s;
        __syncthreads();
        if (wid == 0 && lane < 16) {
            int w = wsum[lane];
            #pragma unroll
            for (int d = 1; d < 16; d <<= 1) {
                int t = __shfl_up(w, d, 64);
                if (lane >= d) w += t;
            }
            wsum[lane] = w;
        }
        __syncthreads();
        const int wpre = (wid == 0) ? 0 : wsum[wid - 1];
        if (idx < NN) offs[idx] = carry + wpre + (s - v);
        carry += wsum[15];
        __syncthreads();
    }
    if (tid == 0) offs[NN] = carry;
}

__global__ __launch_bounds__(256) void scatter_src(
    const int* __restrict__ src, const int* __restrict__ pos_s,
    const int* __restrict__ offs_s, int* __restrict__ eidx_s)
{
    const int e = blockIdx.x * blockDim.x + threadIdx.x;
    if (e >= NE) return;
    eidx_s[offs_s[src[e]] + pos_s[e]] = e;
}

// T bf16, LDS-buffered per block of 16 nodes; final dump is one contiguous
// 33,280-B stream per block (round-3 lesson: scattered 64B writes -> 0.95 TB/s).
__global__ __launch_bounds__(256) void tprep2(
    const float* __restrict__ x, const float* __restrict__ W2R,
    ushort* __restrict__ T)
{
    __shared__ __align__(16) ushort tl[16 * TROW];   // 33,280 B
    const int tid = threadIdx.x;
    const int nl = tid >> 4;          // 0..15 local node
    const int o  = tid & 15;
    const int n  = blockIdx.x * 16 + nl;

    float xr[16];
    {
        const float4* p = reinterpret_cast<const float4*>(x) + (size_t)n * 4;
        float4 a = p[0], b = p[1], c = p[2], d = p[3];
        xr[0]=a.x; xr[1]=a.y; xr[2]=a.z;  xr[3]=a.w;
        xr[4]=b.x; xr[5]=b.y; xr[6]=b.z;  xr[7]=b.w;
        xr[8]=c.x; xr[9]=c.y; xr[10]=c.z; xr[11]=c.w;
        xr[12]=d.x; xr[13]=d.y; xr[14]=d.z; xr[15]=d.w;
    }

    ushort* trow = tl + nl * TROW;
    for (int j = 0; j < 65; ++j) {
        const float4* wp = reinterpret_cast<const float4*>(W2R + j * 256 + o * 16);
        float4 wa = wp[0], wb = wp[1], wc = wp[2], wd = wp[3];
        float s;
        s  = xr[0]*wa.x;           s = fmaf(xr[1],  wa.y, s); s = fmaf(xr[2],  wa.z, s); s = fmaf(xr[3],  wa.w, s);
        s = fmaf(xr[4],  wb.x, s); s = fmaf(xr[5],  wb.y, s); s = fmaf(xr[6],  wb.z, s); s = fmaf(xr[7],  wb.w, s);
        s = fmaf(xr[8],  wc.x, s); s = fmaf(xr[9],  wc.y, s); s = fmaf(xr[10], wc.z, s); s = fmaf(xr[11], wc.w, s);
        s = fmaf(xr[12], wd.x, s); s = fmaf(xr[13], wd.y, s); s = fmaf(xr[14], wd.z, s); s = fmaf(xr[15], wd.w, s);
        trow[j * 16 + o] = f2bf(s);
    }
    __syncthreads();

    // contiguous dump: 16*TROW ushorts = 2080 uint4 chunks
    const uint4* ls = reinterpret_cast<const uint4*>(tl);
    uint4* gd = reinterpret_cast<uint4*>(T + (size_t)blockIdx.x * 16 * TROW);
    for (int c = tid; c < 2080; c += 256) gd[c] = ls[c];
}

// per src-sorted slot k: compute msg, write DIRECTLY to dst-sorted position.
__global__ __launch_bounds__(256) void edge_msg2(
    const int* __restrict__ eidx_s, const int* __restrict__ src,
    const int* __restrict__ dst, const float* __restrict__ ef,
    const float* __restrict__ W1, const float* __restrict__ b1,
    const ushort* __restrict__ T, const int* __restrict__ offs_d,
    int* __restrict__ cur_d, float* __restrict__ msgbuf)
{
    const int k = blockIdx.x * blockDim.x + threadIdx.x;
    if (k >= NE) return;
    const int e = eidx_s[k];
    const int s = src[e];

    float efv[16];
    {
        const float4* p = reinterpret_cast<const float4*>(ef) + (size_t)e * 4;
        float4 a = p[0], b = p[1], c = p[2], d = p[3];
        efv[0]=a.x; efv[1]=a.y; efv[2]=a.z;  efv[3]=a.w;
        efv[4]=b.x; efv[5]=b.y; efv[6]=b.z;  efv[7]=b.w;
        efv[8]=c.x; efv[9]=c.y; efv[10]=c.z; efv[11]=c.w;
        efv[12]=d.x; efv[13]=d.y; efv[14]=d.z; efv[15]=d.w;
    }

    const ushort* tr = T + (size_t)s * TROW;
    float m[16];
    {   // b2 row: j=64 -> ushort offset 1024
        uint4 a = *reinterpret_cast<const uint4*>(tr + 1024);
        uint4 b = *reinterpret_cast<const uint4*>(tr + 1032);
        m[0]=bflo(a.x);  m[1]=bfhi(a.x);  m[2]=bflo(a.y);  m[3]=bfhi(a.y);
        m[4]=bflo(a.z);  m[5]=bfhi(a.z);  m[6]=bflo(a.w);  m[7]=bfhi(a.w);
        m[8]=bflo(b.x);  m[9]=bfhi(b.x);  m[10]=bflo(b.y); m[11]=bfhi(b.y);
        m[12]=bflo(b.z); m[13]=bfhi(b.z); m[14]=bflo(b.w); m[15]=bfhi(b.w);
    }

    for (int j = 0; j < HID; ++j) {
        float hj = b1[j];
        #pragma unroll
        for (int i = 0; i < 16; ++i)
            hj = fmaf(efv[i], W1[i * HID + j], hj);
        hj = fmaxf(hj, 0.f);

        uint4 a = *reinterpret_cast<const uint4*>(tr + j * 16);
        uint4 b = *reinterpret_cast<const uint4*>(tr + j * 16 + 8);
        m[0]  = fmaf(hj, bflo(a.x), m[0]);  m[1]  = fmaf(hj, bfhi(a.x), m[1]);
        m[2]  = fmaf(hj, bflo(a.y), m[2]);  m[3]  = fmaf(hj, bfhi(a.y), m[3]);
        m[4]  = fmaf(hj, bflo(a.z), m[4]);  m[5]  = fmaf(hj, bfhi(a.z), m[5]);
        m[6]  = fmaf(hj, bflo(a.w), m[6]);  m[7]  = fmaf(hj, bfhi(a.w), m[7]);
        m[8]  = fmaf(hj, bflo(b.x), m[8]);  m[9]  = fmaf(hj, bfhi(b.x), m[9]);
        m[10] = fmaf(hj, bflo(b.y), m[10]); m[11] = fmaf(hj, bfhi(b.y), m[11]);
        m[12] = fmaf(hj, bflo(b.z), m[12]); m[13] = fmaf(hj, bfhi(b.z), m[13]);
        m[14] = fmaf(hj, bflo(b.w), m[14]); m[15] = fmaf(hj, bfhi(b.w), m[15]);
    }

    const int d = dst[e];
    const int slot = offs_d[d] + atomicAdd(cur_d + d, 1);
    float4* mr = reinterpret_cast<float4*>(msgbuf + (size_t)slot * 16);
    mr[0] = make_float4(m[0], m[1], m[2], m[3]);
    mr[1] = make_float4(m[4], m[5], m[6], m[7]);
    mr[2] = make_float4(m[8], m[9], m[10], m[11]);
    mr[3] = make_float4(m[12], m[13], m[14], m[15]);
}

// contiguous-range gather: 16 lanes per node stream deg*64B
__global__ __launch_bounds__(256) void gather_mean2(
    const float* __restrict__ msgbuf, const int* __restrict__ offs_d,
    const float* __restrict__ x, const float* __restrict__ bias,
    float* __restrict__ out)
{
    const int t = blockIdx.x * blockDim.x + threadIdx.x;
    if (t >= NN * FOUT) return;
    const int n = t >> 4;
    const int o = t & 15;
    const int beg = offs_d[n], end = offs_d[n + 1];
    float s = 0.f;
    for (int k = beg; k < end; ++k)
        s += msgbuf[(size_t)k * 16 + o];
    const int d = end - beg;
    const float v = (d > 0) ? (s / (float)d) : x[t];
    out[t] = v + bias[o];
}

// ===========================================================================
// FALLBACK (round-2 proven path, ~36.4 MB ws)
// ===========================================================================
__global__ __launch_bounds__(1024) void dgc_scan(
    const int* __restrict__ deg, int* __restrict__ offs, int n)
{
    __shared__ int wsum[16];
    const int tid = threadIdx.x;
    const int lane = tid & 63;
    const int wid = tid >> 6;
    int carry = 0;
    for (int base = 0; base < n; base += 1024) {
        const int idx = base + tid;
        const int v = (idx < n) ? deg[idx] : 0;
        int s = v;
        #pragma unroll
        for (int d = 1; d < 64; d <<= 1) {
            int t = __shfl_up(s, d, 64);
            if (lane >= d) s += t;
        }
        if (lane == 63) wsum[wid] = s;
        __syncthreads();
        if (wid == 0 && lane < 16) {
            int w = wsum[lane];
            #pragma unroll
            for (int d = 1; d < 16; d <<= 1) {
                int t = __shfl_up(w, d, 64);
                if (lane >= d) w += t;
            }
            wsum[lane] = w;
        }
        __syncthreads();
        const int wpre = (wid == 0) ? 0 : wsum[wid - 1];
        if (idx < n) offs[idx] = carry + wpre + (s - v);
        carry += wsum[15];
        __syncthreads();
    }
    if (tid == 0) offs[n] = carry;
}

__global__ __launch_bounds__(256) void dgc_edge_csr(
    const float* __restrict__ x, const float* __restrict__ ef,
    const int* __restrict__ src, const int* __restrict__ dst,
    const float* __restrict__ W1, const float* __restrict__ b1,
    const float* __restrict__ W2, const float* __restrict__ b2,
    float* __restrict__ msg, int* __restrict__ pos, int* __restrict__ deg)
{
    const int e = blockIdx.x * blockDim.x + threadIdx.x;
    if (e >= NE) return;
    float efv[16];
    {
        const float4* p = reinterpret_cast<const float4*>(ef) + (size_t)e * 4;
        float4 a = p[0], b = p[1], c = p[2], d = p[3];
        efv[0]=a.x; efv[1]=a.y; efv[2]=a.z;  efv[3]=a.w;
        efv[4]=b.x; efv[5]=b.y; efv[6]=b.z;  efv[7]=b.w;
        efv[8]=c.x; efv[9]=c.y; efv[10]=c.z; efv[11]=c.w;
        efv[12]=d.x; efv[13]=d.y; efv[14]=d.z; efv[15]=d.w;
    }
    const int s = src[e];
    float xs[16];
    {
        const float4* p = reinterpret_cast<const float4*>(x) + (size_t)s * 4;
        float4 a = p[0], b = p[1], c = p[2], d = p[3];
        xs[0]=a.x; xs[1]=a.y; xs[2]=a.z;  xs[3]=a.w;
        xs[4]=b.x; xs[5]=b.y; xs[6]=b.z;  xs[7]=b.w;
        xs[8]=c.x; xs[9]=c.y; xs[10]=c.z; xs[11]=c.w;
        xs[12]=d.x; xs[13]=d.y; xs[14]=d.z; xs[15]=d.w;
    }
    float m[16];
    #pragma unroll
    for (int o = 0; o < 16; ++o) m[o] = 0.f;
    #pragma unroll
    for (int i = 0; i < 16; ++i) {
        const float xi = xs[i];
        #pragma unroll
        for (int o = 0; o < 16; ++o) m[o] = fmaf(xi, b2[i * 16 + o], m[o]);
    }
    for (int j = 0; j < HID; ++j) {
        float hj = b1[j];
        #pragma unroll
        for (int i = 0; i < 16; ++i) hj = fmaf(efv[i], W1[i * HID + j], hj);
        hj = fmaxf(hj, 0.f);
        const float* __restrict__ w2r = W2 + (size_t)j * 256;
        float t[16];
        #pragma unroll
        for (int o = 0; o < 16; ++o) t[o] = 0.f;
        #pragma unroll
        for (int i = 0; i < 16; ++i) {
            const float xi = xs[i];
            #pragma unroll
            for (int o = 0; o < 16; ++o) t[o] = fmaf(xi, w2r[i * 16 + o], t[o]);
        }
        #pragma unroll
        for (int o = 0; o < 16; ++o) m[o] = fmaf(hj, t[o], m[o]);
    }
    float4* mr = reinterpret_cast<float4*>(msg + (size_t)e * 16);
    mr[0] = make_float4(m[0], m[1], m[2], m[3]);
    mr[1] = make_float4(m[4], m[5], m[6], m[7]);
    mr[2] = make_float4(m[8], m[9], m[10], m[11]);
    mr[3] = make_float4(m[12], m[13], m[14], m[15]);
    pos[e] = atomicAdd(deg + dst[e], 1);
}

__global__ __launch_bounds__(256) void dgc_scatter(
    const int* __restrict__ dst, const int* __restrict__ pos,
    const int* __restrict__ offs, int* __restrict__ eidx)
{
    const int e = blockIdx.x * blockDim.x + threadIdx.x;
    if (e >= NE) return;
    eidx[offs[dst[e]] + pos[e]] = e;
}

__global__ __launch_bounds__(256) void dgc_gather(
    const float* __restrict__ msg, const int* __restrict__ offs,
    const int* __restrict__ eidx, const float* __restrict__ x,
    const float* __restrict__ bias, float* __restrict__ out)
{
    const int t = blockIdx.x * blockDim.x + threadIdx.x;
    if (t >= NN * FOUT) return;
    const int n = t >> 4;
    const int o = t & 15;
    const int beg = offs[n], end = offs[n + 1];
    float s = 0.f;
    for (int k = beg; k < end; ++k)
        s += msg[(size_t)eidx[k] * 16 + o];
    const int d = end - beg;
    const float v = (d > 0) ? (s / (float)d) : x[t];
    out[t] = v + bias[o];
}

extern "C" void kernel_launch(void* const* d_in, const int* in_sizes, int n_in,
                              void* d_out, int out_size, void* d_ws, size_t ws_size,
                              hipStream_t stream) {
    const float* x    = (const float*)d_in[0];
    const float* ef   = (const float*)d_in[1];
    const int*   src  = (const int*)d_in[2];
    const int*   dst  = (const int*)d_in[3];
    const float* W1   = (const float*)d_in[4];
    const float* b1   = (const float*)d_in[5];
    const float* W2   = (const float*)d_in[6];
    const float* b2   = (const float*)d_in[7];
    const float* bias = (const float*)d_in[8];
    float* out = (float*)d_out;

    // main-path ws layout
    ushort* T      = (ushort*)d_ws;                       // NN*TROW bf16 (104 MB)
    float*  msgbuf = (float*)(T + (size_t)NN * TROW);     // NE*16 f32   (32 MB)
    float*  W2R    = msgbuf + (size_t)NE * 16;            // 65*256
    int*    deg_s  = (int*)(W2R + 65 * 256);              // NN
    int*    deg_d  = deg_s + NN;                          // NN
    int*    cur_d  = deg_d + NN;                          // NN
    int*    offs_s = cur_d + NN;                          // NN+1
    int*    offs_d = offs_s + NN + 1;                     // NN+1
    int*    pos_s  = offs_d + NN + 1;                     // NE
    int*    eidx_s = pos_s + NE;                          // NE
    const size_t needed =
        (size_t)NN * TROW * 2 +
        ((size_t)NE * 16 + 65 * 256) * 4 +
        ((size_t)3 * NN + 2 * (NN + 1) + (size_t)2 * NE) * 4;

    if (ws_size >= needed) {
        hipMemsetAsync(deg_s, 0, (size_t)3 * NN * sizeof(int), stream);  // deg_s,deg_d,cur_d
        w2r_prep<<<(65 * 256 + 255) / 256, 256, 0, stream>>>(W2, b2, W2R);
        count_both<<<(NE + 255) / 256, 256, 0, stream>>>(src, dst, deg_s, pos_s, deg_d);
        dgc_scan2<<<2, 1024, 0, stream>>>(deg_s, offs_s, deg_d, offs_d);
        scatter_src<<<(NE + 255) / 256, 256, 0, stream>>>(src, pos_s, offs_s, eidx_s);
        tprep2<<<NN / 16, 256, 0, stream>>>(x, W2R, T);
        edge_msg2<<<(NE + 255) / 256, 256, 0, stream>>>(
            eidx_s, src, dst, ef, W1, b1, T, offs_d, cur_d, msgbuf);
        gather_mean2<<<(NN * FOUT + 255) / 256, 256, 0, stream>>>(
            msgbuf, offs_d, x, bias, out);
    } else {
        // round-2 fallback
        float* msg  = (float*)d_ws;
        int*   deg  = (int*)(msg + (size_t)NE * 16);
        int*   offs = deg + NN;
        int*   pos  = offs + NN + 1;
        int*   eidx = pos + NE;
        hipMemsetAsync(deg, 0, (size_t)NN * sizeof(int), stream);
        dgc_edge_csr<<<(NE + 255) / 256, 256, 0, stream>>>(
            x, ef, src, dst, W1, b1, W2, b2, msg, pos, deg);
        dgc_scan<<<1, 1024, 0, stream>>>(deg, offs, NN);
        dgc_scatter<<<(NE + 255) / 256, 256, 0, stream>>>(dst, pos, offs, eidx);
        dgc_gather<<<(NN * FOUT + 255) / 256, 256, 0, stream>>>(
            msg, offs, eidx, x, bias, out);
    }
}

// Round 5
// 288.062 us; speedup vs baseline: 1.6571x; 1.3392x over previous
//
#include <hip/hip_runtime.h>

#define NN 50000
#define NE 500000
#define FIN 16
#define FOUT 16
#define HID 64
#define TROW 1040   // (HID+1)*16 elems per node: j=0..63 = W2 part, j=64 = b2 part
#define JCH 13      // j-chunk for LDS staging: 65 = 5*13 exactly

typedef unsigned int  uint;
typedef unsigned short ushort;

__device__ __forceinline__ ushort f2bf(float f) {   // RNE f32->bf16
    uint u = __float_as_uint(f);
    u += 0x7fffu + ((u >> 16) & 1u);
    return (ushort)(u >> 16);
}
__device__ __forceinline__ float bflo(uint u) { return __uint_as_float(u << 16); }
__device__ __forceinline__ float bfhi(uint u) { return __uint_as_float(u & 0xffff0000u); }

// ===========================================================================
// MAIN PATH (~237 MB ws). Factorized: msg[e,o] = T[s][64][o] + sum_j h_j*T[s][j][o]
// T stored bf16 (104 MB). Round-4 lesson: tprep was L1-transaction-bound on
// 64B-strided W2R reads (66.5KB > L1, 16 lines touched per load instr) ->
// round 5 stages W2R through LDS in 13-row chunks, padded [o][20] layout.
// ===========================================================================

// W2R[j][o][i] = W2[j][i*16+o] (j<64), b2[i*16+o] (j==64)
__global__ __launch_bounds__(256) void w2r_prep(
    const float* __restrict__ W2, const float* __restrict__ b2,
    float* __restrict__ W2R)
{
    const int t = blockIdx.x * blockDim.x + threadIdx.x;
    if (t >= 65 * 256) return;
    const int j = t >> 8;
    const int col = t & 255;          // col = i*16 + o
    const int i = col >> 4, o = col & 15;
    const float v = (j < 64) ? W2[j * 256 + col] : b2[col];
    W2R[j * 256 + o * 16 + i] = v;
}

// one pass: src ranks (for src-sort) + dst degree histogram
__global__ __launch_bounds__(256) void count_both(
    const int* __restrict__ src, const int* __restrict__ dst,
    int* __restrict__ deg_s, int* __restrict__ pos_s, int* __restrict__ deg_d)
{
    const int e = blockIdx.x * blockDim.x + threadIdx.x;
    if (e >= NE) return;
    pos_s[e] = atomicAdd(deg_s + src[e], 1);
    atomicAdd(deg_d + dst[e], 1);
}

// two independent exclusive scans (block 0: A, block 1: B), n=NN each
__global__ __launch_bounds__(1024) void dgc_scan2(
    const int* __restrict__ degA, int* __restrict__ offA,
    const int* __restrict__ degB, int* __restrict__ offB)
{
    const int* __restrict__ deg = blockIdx.x ? degB : degA;
    int* __restrict__ offs      = blockIdx.x ? offB : offA;
    __shared__ int wsum[16];
    const int tid = threadIdx.x;
    const int lane = tid & 63;
    const int wid = tid >> 6;
    int carry = 0;
    for (int base = 0; base < NN; base += 1024) {
        const int idx = base + tid;
        const int v = (idx < NN) ? deg[idx] : 0;
        int s = v;
        #pragma unroll
        for (int d = 1; d < 64; d <<= 1) {
            int t = __shfl_up(s, d, 64);
            if (lane >= d) s += t;
        }
        if (lane == 63) wsum[wid] = s;
        __syncthreads();
        if (wid == 0 && lane < 16) {
            int w = wsum[lane];
            #pragma unroll
            for (int d = 1; d < 16; d <<= 1) {
                int t = __shfl_up(w, d, 64);
                if (lane >= d) w += t;
            }
            wsum[lane] = w;
        }
        __syncthreads();
        const int wpre = (wid == 0) ? 0 : wsum[wid - 1];
        if (idx < NN) offs[idx] = carry + wpre + (s - v);
        carry += wsum[15];
        __syncthreads();
    }
    if (tid == 0) offs[NN] = carry;
}

__global__ __launch_bounds__(256) void scatter_src(
    const int* __restrict__ src, const int* __restrict__ pos_s,
    const int* __restrict__ offs_s, int* __restrict__ eidx_s)
{
    const int e = blockIdx.x * blockDim.x + threadIdx.x;
    if (e >= NE) return;
    eidx_s[offs_s[src[e]] + pos_s[e]] = e;
}

// T bf16; W2R staged through LDS in 5 chunks of 13 j-rows; output tile in LDS,
// dumped as one contiguous 33,280-B stream per 16-node block.
__global__ __launch_bounds__(256) void tprep3(
    const float* __restrict__ x, const float* __restrict__ W2R,
    ushort* __restrict__ T)
{
    __shared__ __align__(16) ushort tl[16 * TROW];          // 33,280 B
    __shared__ __align__(16) float  w2s[JCH * 16 * 20];     // 16,640 B, [jj][o][20]
    const int tid = threadIdx.x;
    const int nl = tid >> 4;          // 0..15 local node
    const int o  = tid & 15;
    const int n  = blockIdx.x * 16 + nl;

    float xr[16];
    {
        const float4* p = reinterpret_cast<const float4*>(x) + (size_t)n * 4;
        float4 a = p[0], b = p[1], c = p[2], d = p[3];
        xr[0]=a.x; xr[1]=a.y; xr[2]=a.z;  xr[3]=a.w;
        xr[4]=b.x; xr[5]=b.y; xr[6]=b.z;  xr[7]=b.w;
        xr[8]=c.x; xr[9]=c.y; xr[10]=c.z; xr[11]=c.w;
        xr[12]=d.x; xr[13]=d.y; xr[14]=d.z; xr[15]=d.w;
    }

    ushort* trow = tl + nl * TROW;
    for (int c = 0; c < 5; ++c) {
        const int j0 = c * JCH;
        // stage 13 j-rows (3328 floats) coalesced -> LDS padded layout
        for (int g = tid; g < JCH * 256; g += 256) {
            const int jj = g >> 8;
            const int col = g & 255;          // col = oo*16 + ii in W2R row
            const int oo = col >> 4, ii = col & 15;
            w2s[jj * 320 + oo * 20 + ii] = W2R[(size_t)(j0 + jj) * 256 + col];
        }
        __syncthreads();

        #pragma unroll
        for (int jj = 0; jj < JCH; ++jj) {
            const float4* wp = reinterpret_cast<const float4*>(w2s + jj * 320 + o * 20);
            float4 wa = wp[0], wb = wp[1], wc = wp[2], wd = wp[3];
            float s;
            s  = xr[0]*wa.x;           s = fmaf(xr[1],  wa.y, s); s = fmaf(xr[2],  wa.z, s); s = fmaf(xr[3],  wa.w, s);
            s = fmaf(xr[4],  wb.x, s); s = fmaf(xr[5],  wb.y, s); s = fmaf(xr[6],  wb.z, s); s = fmaf(xr[7],  wb.w, s);
            s = fmaf(xr[8],  wc.x, s); s = fmaf(xr[9],  wc.y, s); s = fmaf(xr[10], wc.z, s); s = fmaf(xr[11], wc.w, s);
            s = fmaf(xr[12], wd.x, s); s = fmaf(xr[13], wd.y, s); s = fmaf(xr[14], wd.z, s); s = fmaf(xr[15], wd.w, s);
            trow[(j0 + jj) * 16 + o] = f2bf(s);
        }
        __syncthreads();   // before next chunk overwrites w2s
    }

    // contiguous dump: 16*TROW ushorts = 2080 uint4 chunks
    const uint4* ls = reinterpret_cast<const uint4*>(tl);
    uint4* gd = reinterpret_cast<uint4*>(T + (size_t)blockIdx.x * 16 * TROW);
    for (int c = tid; c < 2080; c += 256) gd[c] = ls[c];
}

// per src-sorted slot k: compute msg, write DIRECTLY to dst-sorted position.
__global__ __launch_bounds__(256) void edge_msg2(
    const int* __restrict__ eidx_s, const int* __restrict__ src,
    const int* __restrict__ dst, const float* __restrict__ ef,
    const float* __restrict__ W1, const float* __restrict__ b1,
    const ushort* __restrict__ T, const int* __restrict__ offs_d,
    int* __restrict__ cur_d, float* __restrict__ msgbuf)
{
    const int k = blockIdx.x * blockDim.x + threadIdx.x;
    if (k >= NE) return;
    const int e = eidx_s[k];
    const int s = src[e];

    float efv[16];
    {
        const float4* p = reinterpret_cast<const float4*>(ef) + (size_t)e * 4;
        float4 a = p[0], b = p[1], c = p[2], d = p[3];
        efv[0]=a.x; efv[1]=a.y; efv[2]=a.z;  efv[3]=a.w;
        efv[4]=b.x; efv[5]=b.y; efv[6]=b.z;  efv[7]=b.w;
        efv[8]=c.x; efv[9]=c.y; efv[10]=c.z; efv[11]=c.w;
        efv[12]=d.x; efv[13]=d.y; efv[14]=d.z; efv[15]=d.w;
    }

    const ushort* tr = T + (size_t)s * TROW;
    float m[16];
    {   // b2 row: j=64 -> ushort offset 1024
        uint4 a = *reinterpret_cast<const uint4*>(tr + 1024);
        uint4 b = *reinterpret_cast<const uint4*>(tr + 1032);
        m[0]=bflo(a.x);  m[1]=bfhi(a.x);  m[2]=bflo(a.y);  m[3]=bfhi(a.y);
        m[4]=bflo(a.z);  m[5]=bfhi(a.z);  m[6]=bflo(a.w);  m[7]=bfhi(a.w);
        m[8]=bflo(b.x);  m[9]=bfhi(b.x);  m[10]=bflo(b.y); m[11]=bfhi(b.y);
        m[12]=bflo(b.z); m[13]=bfhi(b.z); m[14]=bflo(b.w); m[15]=bfhi(b.w);
    }

    for (int j = 0; j < HID; ++j) {
        float hj = b1[j];
        #pragma unroll
        for (int i = 0; i < 16; ++i)
            hj = fmaf(efv[i], W1[i * HID + j], hj);
        hj = fmaxf(hj, 0.f);

        uint4 a = *reinterpret_cast<const uint4*>(tr + j * 16);
        uint4 b = *reinterpret_cast<const uint4*>(tr + j * 16 + 8);
        m[0]  = fmaf(hj, bflo(a.x), m[0]);  m[1]  = fmaf(hj, bfhi(a.x), m[1]);
        m[2]  = fmaf(hj, bflo(a.y), m[2]);  m[3]  = fmaf(hj, bfhi(a.y), m[3]);
        m[4]  = fmaf(hj, bflo(a.z), m[4]);  m[5]  = fmaf(hj, bfhi(a.z), m[5]);
        m[6]  = fmaf(hj, bflo(a.w), m[6]);  m[7]  = fmaf(hj, bfhi(a.w), m[7]);
        m[8]  = fmaf(hj, bflo(b.x), m[8]);  m[9]  = fmaf(hj, bfhi(b.x), m[9]);
        m[10] = fmaf(hj, bflo(b.y), m[10]); m[11] = fmaf(hj, bfhi(b.y), m[11]);
        m[12] = fmaf(hj, bflo(b.z), m[12]); m[13] = fmaf(hj, bfhi(b.z), m[13]);
        m[14] = fmaf(hj, bflo(b.w), m[14]); m[15] = fmaf(hj, bfhi(b.w), m[15]);
    }

    const int d = dst[e];
    const int slot = offs_d[d] + atomicAdd(cur_d + d, 1);
    float4* mr = reinterpret_cast<float4*>(msgbuf + (size_t)slot * 16);
    mr[0] = make_float4(m[0], m[1], m[2], m[3]);
    mr[1] = make_float4(m[4], m[5], m[6], m[7]);
    mr[2] = make_float4(m[8], m[9], m[10], m[11]);
    mr[3] = make_float4(m[12], m[13], m[14], m[15]);
}

// contiguous-range gather: 16 lanes per node stream deg*64B
__global__ __launch_bounds__(256) void gather_mean2(
    const float* __restrict__ msgbuf, const int* __restrict__ offs_d,
    const float* __restrict__ x, const float* __restrict__ bias,
    float* __restrict__ out)
{
    const int t = blockIdx.x * blockDim.x + threadIdx.x;
    if (t >= NN * FOUT) return;
    const int n = t >> 4;
    const int o = t & 15;
    const int beg = offs_d[n], end = offs_d[n + 1];
    float s = 0.f;
    for (int k = beg; k < end; ++k)
        s += msgbuf[(size_t)k * 16 + o];
    const int d = end - beg;
    const float v = (d > 0) ? (s / (float)d) : x[t];
    out[t] = v + bias[o];
}

// ===========================================================================
// FALLBACK (round-2 proven path, ~36.4 MB ws)
// ===========================================================================
__global__ __launch_bounds__(1024) void dgc_scan(
    const int* __restrict__ deg, int* __restrict__ offs, int n)
{
    __shared__ int wsum[16];
    const int tid = threadIdx.x;
    const int lane = tid & 63;
    const int wid = tid >> 6;
    int carry = 0;
    for (int base = 0; base < n; base += 1024) {
        const int idx = base + tid;
        const int v = (idx < n) ? deg[idx] : 0;
        int s = v;
        #pragma unroll
        for (int d = 1; d < 64; d <<= 1) {
            int t = __shfl_up(s, d, 64);
            if (lane >= d) s += t;
        }
        if (lane == 63) wsum[wid] = s;
        __syncthreads();
        if (wid == 0 && lane < 16) {
            int w = wsum[lane];
            #pragma unroll
            for (int d = 1; d < 16; d <<= 1) {
                int t = __shfl_up(w, d, 64);
                if (lane >= d) w += t;
            }
            wsum[lane] = w;
        }
        __syncthreads();
        const int wpre = (wid == 0) ? 0 : wsum[wid - 1];
        if (idx < n) offs[idx] = carry + wpre + (s - v);
        carry += wsum[15];
        __syncthreads();
    }
    if (tid == 0) offs[n] = carry;
}

__global__ __launch_bounds__(256) void dgc_edge_csr(
    const float* __restrict__ x, const float* __restrict__ ef,
    const int* __restrict__ src, const int* __restrict__ dst,
    const float* __restrict__ W1, const float* __restrict__ b1,
    const float* __restrict__ W2, const float* __restrict__ b2,
    float* __restrict__ msg, int* __restrict__ pos, int* __restrict__ deg)
{
    const int e = blockIdx.x * blockDim.x + threadIdx.x;
    if (e >= NE) return;
    float efv[16];
    {
        const float4* p = reinterpret_cast<const float4*>(ef) + (size_t)e * 4;
        float4 a = p[0], b = p[1], c = p[2], d = p[3];
        efv[0]=a.x; efv[1]=a.y; efv[2]=a.z;  efv[3]=a.w;
        efv[4]=b.x; efv[5]=b.y; efv[6]=b.z;  efv[7]=b.w;
        efv[8]=c.x; efv[9]=c.y; efv[10]=c.z; efv[11]=c.w;
        efv[12]=d.x; efv[13]=d.y; efv[14]=d.z; efv[15]=d.w;
    }
    const int s = src[e];
    float xs[16];
    {
        const float4* p = reinterpret_cast<const float4*>(x) + (size_t)s * 4;
        float4 a = p[0], b = p[1], c = p[2], d = p[3];
        xs[0]=a.x; xs[1]=a.y; xs[2]=a.z;  xs[3]=a.w;
        xs[4]=b.x; xs[5]=b.y; xs[6]=b.z;  xs[7]=b.w;
        xs[8]=c.x; xs[9]=c.y; xs[10]=c.z; xs[11]=c.w;
        xs[12]=d.x; xs[13]=d.y; xs[14]=d.z; xs[15]=d.w;
    }
    float m[16];
    #pragma unroll
    for (int o = 0; o < 16; ++o) m[o] = 0.f;
    #pragma unroll
    for (int i = 0; i < 16; ++i) {
        const float xi = xs[i];
        #pragma unroll
        for (int o = 0; o < 16; ++o) m[o] = fmaf(xi, b2[i * 16 + o], m[o]);
    }
    for (int j = 0; j < HID; ++j) {
        float hj = b1[j];
        #pragma unroll
        for (int i = 0; i < 16; ++i) hj = fmaf(efv[i], W1[i * HID + j], hj);
        hj = fmaxf(hj, 0.f);
        const float* __restrict__ w2r = W2 + (size_t)j * 256;
        float t[16];
        #pragma unroll
        for (int o = 0; o < 16; ++o) t[o] = 0.f;
        #pragma unroll
        for (int i = 0; i < 16; ++i) {
            const float xi = xs[i];
            #pragma unroll
            for (int o = 0; o < 16; ++o) t[o] = fmaf(xi, w2r[i * 16 + o], t[o]);
        }
        #pragma unroll
        for (int o = 0; o < 16; ++o) m[o] = fmaf(hj, t[o], m[o]);
    }
    float4* mr = reinterpret_cast<float4*>(msg + (size_t)e * 16);
    mr[0] = make_float4(m[0], m[1], m[2], m[3]);
    mr[1] = make_float4(m[4], m[5], m[6], m[7]);
    mr[2] = make_float4(m[8], m[9], m[10], m[11]);
    mr[3] = make_float4(m[12], m[13], m[14], m[15]);
    pos[e] = atomicAdd(deg + dst[e], 1);
}

__global__ __launch_bounds__(256) void dgc_scatter(
    const int* __restrict__ dst, const int* __restrict__ pos,
    const int* __restrict__ offs, int* __restrict__ eidx)
{
    const int e = blockIdx.x * blockDim.x + threadIdx.x;
    if (e >= NE) return;
    eidx[offs[dst[e]] + pos[e]] = e;
}

__global__ __launch_bounds__(256) void dgc_gather(
    const float* __restrict__ msg, const int* __restrict__ offs,
    const int* __restrict__ eidx, const float* __restrict__ x,
    const float* __restrict__ bias, float* __restrict__ out)
{
    const int t = blockIdx.x * blockDim.x + threadIdx.x;
    if (t >= NN * FOUT) return;
    const int n = t >> 4;
    const int o = t & 15;
    const int beg = offs[n], end = offs[n + 1];
    float s = 0.f;
    for (int k = beg; k < end; ++k)
        s += msg[(size_t)eidx[k] * 16 + o];
    const int d = end - beg;
    const float v = (d > 0) ? (s / (float)d) : x[t];
    out[t] = v + bias[o];
}

extern "C" void kernel_launch(void* const* d_in, const int* in_sizes, int n_in,
                              void* d_out, int out_size, void* d_ws, size_t ws_size,
                              hipStream_t stream) {
    const float* x    = (const float*)d_in[0];
    const float* ef   = (const float*)d_in[1];
    const int*   src  = (const int*)d_in[2];
    const int*   dst  = (const int*)d_in[3];
    const float* W1   = (const float*)d_in[4];
    const float* b1   = (const float*)d_in[5];
    const float* W2   = (const float*)d_in[6];
    const float* b2   = (const float*)d_in[7];
    const float* bias = (const float*)d_in[8];
    float* out = (float*)d_out;

    // main-path ws layout
    ushort* T      = (ushort*)d_ws;                       // NN*TROW bf16 (104 MB)
    float*  msgbuf = (float*)(T + (size_t)NN * TROW);     // NE*16 f32   (32 MB)
    float*  W2R    = msgbuf + (size_t)NE * 16;            // 65*256
    int*    deg_s  = (int*)(W2R + 65 * 256);              // NN
    int*    deg_d  = deg_s + NN;                          // NN
    int*    cur_d  = deg_d + NN;                          // NN
    int*    offs_s = cur_d + NN;                          // NN+1
    int*    offs_d = offs_s + NN + 1;                     // NN+1
    int*    pos_s  = offs_d + NN + 1;                     // NE
    int*    eidx_s = pos_s + NE;                          // NE
    const size_t needed =
        (size_t)NN * TROW * 2 +
        ((size_t)NE * 16 + 65 * 256) * 4 +
        ((size_t)3 * NN + 2 * (NN + 1) + (size_t)2 * NE) * 4;

    if (ws_size >= needed) {
        hipMemsetAsync(deg_s, 0, (size_t)3 * NN * sizeof(int), stream);  // deg_s,deg_d,cur_d
        w2r_prep<<<(65 * 256 + 255) / 256, 256, 0, stream>>>(W2, b2, W2R);
        count_both<<<(NE + 255) / 256, 256, 0, stream>>>(src, dst, deg_s, pos_s, deg_d);
        dgc_scan2<<<2, 1024, 0, stream>>>(deg_s, offs_s, deg_d, offs_d);
        scatter_src<<<(NE + 255) / 256, 256, 0, stream>>>(src, pos_s, offs_s, eidx_s);
        tprep3<<<NN / 16, 256, 0, stream>>>(x, W2R, T);
        edge_msg2<<<(NE + 255) / 256, 256, 0, stream>>>(
            eidx_s, src, dst, ef, W1, b1, T, offs_d, cur_d, msgbuf);
        gather_mean2<<<(NN * FOUT + 255) / 256, 256, 0, stream>>>(
            msgbuf, offs_d, x, bias, out);
    } else {
        // round-2 fallback
        float* msg  = (float*)d_ws;
        int*   deg  = (int*)(msg + (size_t)NE * 16);
        int*   offs = deg + NN;
        int*   pos  = offs + NN + 1;
        int*   eidx = pos + NE;
        hipMemsetAsync(deg, 0, (size_t)NN * sizeof(int), stream);
        dgc_edge_csr<<<(NE + 255) / 256, 256, 0, stream>>>(
            x, ef, src, dst, W1, b1, W2, b2, msg, pos, deg);
        dgc_scan<<<1, 1024, 0, stream>>>(deg, offs, NN);
        dgc_scatter<<<(NE + 255) / 256, 256, 0, stream>>>(dst, pos, offs, eidx);
        dgc_gather<<<(NN * FOUT + 255) / 256, 256, 0, stream>>>(
            msg, offs, eidx, x, bias, out);
    }
}